// Round 3
// baseline (238.684 us; speedup 1.0000x reference)
//
#include <hip/hip_runtime.h>
#include <math.h>

// LinearAttend: B=4, N=8, D=64, S=8192, fp32 in/out.
// out[j,s] = (QSCALE/W_s) * sum_i (ctx[i,j]/Z_i) * exp(q[i,s])
//   ctx[i,j] = sum_s exp(k[i,s]) * v[j,s],  Z_i = sum_s exp(k[i,s])
// 3-kernel pipeline, zero atomics:
//   1) ctx_partial: per-(head,chunk) 64x64 fp16-MFMA partials -> ws (plain stores)
//   2) reduce: sum 16 chunk-partials, fold 1/Z, emit fp16 czT[j][i]
//   3) out: fp16 MFMA, A-frags straight from global czT, 2 barriers/round

typedef _Float16 half8 __attribute__((ext_vector_type(8)));
typedef float floatx4 __attribute__((ext_vector_type(4)));

constexpr int BHEADS = 32;
constexpr int DH     = 64;
constexpr int SEQ    = 8192;
constexpr int NCHUNK = 16;          // split-K chunks of 512 s
constexpr float QSCALE = 0.125f;    // 64^-0.5

// ---------------------------------------------------------------------------
// Kernel 1: partial[head][chunk][i][j] = sum_{s in chunk} e[i,s]*v[j,s]
//           Zp[head][chunk][i]         = sum_{s in chunk} e[i,s]
// grid (16 chunks x 32 heads), 256 thr, 8 rounds of 64 s, depth-1 prefetch.
// ---------------------------------------------------------------------------
__global__ __launch_bounds__(256)
void ctx_partial_kernel(const float* __restrict__ K, const float* __restrict__ V,
                        float* __restrict__ partial, float* __restrict__ Zp)
{
    const int head  = blockIdx.y;
    const int chunk = blockIdx.x;
    const int t     = threadIdx.x;
    const int lane  = t & 63;
    const int w     = t >> 6;
    const int ln    = lane & 15;
    const int q8    = lane >> 4;

    const float* kh = K + (size_t)head * DH * SEQ;
    const float* vh = V + (size_t)head * DH * SEQ;

    __shared__ __align__(16) _Float16 et[64 * 72];  // stride 72 halves = 144 B
    __shared__ __align__(16) _Float16 vt[64 * 72];
    __shared__ __align__(16) float zred[64 * 8];

    // staging map: rows {r0, r0+32}, cols c0..c0+7 (half8 b128 writes)
    const int r0 = t >> 3;           // 0..31
    const int c0 = 8 * (t & 7);      // 0..56
    const int s_blk = chunk * 512;

    float4 pk[2][2], pv[2][2];
    #pragma unroll
    for (int rr = 0; rr < 2; ++rr) {
        const size_t base = (size_t)(r0 + 32 * rr) * SEQ + s_blk + c0;
        pk[rr][0] = *(const float4*)(kh + base);
        pk[rr][1] = *(const float4*)(kh + base + 4);
        pv[rr][0] = *(const float4*)(vh + base);
        pv[rr][1] = *(const float4*)(vh + base + 4);
    }

    floatx4 acc[4];
    #pragma unroll
    for (int jt = 0; jt < 4; ++jt) acc[jt] = (floatx4){0.f, 0.f, 0.f, 0.f};
    float zacc[2] = {0.f, 0.f};

    for (int ts = 0; ts < 8; ++ts) {
        #pragma unroll
        for (int rr = 0; rr < 2; ++rr) {
            const int row = r0 + 32 * rr;
            float e[8];
            e[0] = __expf(pk[rr][0].x); e[1] = __expf(pk[rr][0].y);
            e[2] = __expf(pk[rr][0].z); e[3] = __expf(pk[rr][0].w);
            e[4] = __expf(pk[rr][1].x); e[5] = __expf(pk[rr][1].y);
            e[6] = __expf(pk[rr][1].z); e[7] = __expf(pk[rr][1].w);
            zacc[rr] += e[0]+e[1]+e[2]+e[3]+e[4]+e[5]+e[6]+e[7];
            half8 he, hv;
            #pragma unroll
            for (int x = 0; x < 4; ++x) {
                he[x] = (_Float16)e[x]; he[x+4] = (_Float16)e[x+4];
            }
            hv[0] = (_Float16)pv[rr][0].x; hv[1] = (_Float16)pv[rr][0].y;
            hv[2] = (_Float16)pv[rr][0].z; hv[3] = (_Float16)pv[rr][0].w;
            hv[4] = (_Float16)pv[rr][1].x; hv[5] = (_Float16)pv[rr][1].y;
            hv[6] = (_Float16)pv[rr][1].z; hv[7] = (_Float16)pv[rr][1].w;
            *(half8*)(et + row * 72 + c0) = he;
            *(half8*)(vt + row * 72 + c0) = hv;
        }
        __syncthreads();
        if (ts < 7) {
            #pragma unroll
            for (int rr = 0; rr < 2; ++rr) {
                const size_t base = (size_t)(r0 + 32 * rr) * SEQ + s_blk
                                    + (ts + 1) * 64 + c0;
                pk[rr][0] = *(const float4*)(kh + base);
                pk[rr][1] = *(const float4*)(kh + base + 4);
                pv[rr][0] = *(const float4*)(vh + base);
                pv[rr][1] = *(const float4*)(vh + base + 4);
            }
        }
        #pragma unroll
        for (int st = 0; st < 2; ++st) {
            const half8 a = *(const half8*)(et + (16 * w + ln) * 72 + st * 32 + q8 * 8);
            #pragma unroll
            for (int jt = 0; jt < 4; ++jt) {
                const half8 b = *(const half8*)(vt + (16 * jt + ln) * 72 + st * 32 + q8 * 8);
                acc[jt] = __builtin_amdgcn_mfma_f32_16x16x32_f16(a, b, acc[jt], 0, 0, 0);
            }
        }
        __syncthreads();
    }

    // coalesced plain stores of the 64x64 partial
    float* ph = partial + (size_t)(head * NCHUNK + chunk) * DH * DH;
    #pragma unroll
    for (int jt = 0; jt < 4; ++jt) {
        #pragma unroll
        for (int rr = 0; rr < 4; ++rr) {
            const int i = 16 * w + q8 * 4 + rr;
            const int j = 16 * jt + ln;
            ph[i * DH + j] = acc[jt][rr];
        }
    }
    zred[r0 * 8 + (t & 7)] = zacc[0];
    zred[(r0 + 32) * 8 + (t & 7)] = zacc[1];
    __syncthreads();
    if (t < 64) {
        const float4 z0 = *(const float4*)(zred + t * 8);
        const float4 z1 = *(const float4*)(zred + t * 8 + 4);
        Zp[(head * NCHUNK + chunk) * DH + t] =
            z0.x + z0.y + z0.z + z0.w + z1.x + z1.y + z1.z + z1.w;
    }
}

// ---------------------------------------------------------------------------
// Kernel 2: czT[head][j][i] = (1/Z_i) * sum_c partial[head][c][i][j]  (fp16)
// grid (32 heads), 256 thr. Partials are L2-resident (8 MiB).
// ---------------------------------------------------------------------------
__global__ __launch_bounds__(256)
void reduce_kernel(const float* __restrict__ partial, const float* __restrict__ Zp,
                   _Float16* __restrict__ czT)
{
    const int h = blockIdx.x;
    const int t = threadIdx.x;
    __shared__ float rz[64];

    if (t < 64) {
        float z = 0.f;
        #pragma unroll
        for (int c = 0; c < NCHUNK; ++c)
            z += Zp[(h * NCHUNK + c) * DH + t];
        rz[t] = 1.0f / z;
    }
    __syncthreads();

    const float* ph = partial + (size_t)h * NCHUNK * DH * DH;
    _Float16* ct = czT + (size_t)h * DH * DH;
    #pragma unroll
    for (int rep = 0; rep < 4; ++rep) {
        const int idx = t + 256 * rep;     // 0..1023 float4 slots
        const int i   = idx >> 4;
        const int j4  = idx & 15;
        float4 sum = {0.f, 0.f, 0.f, 0.f};
        #pragma unroll
        for (int c = 0; c < NCHUNK; ++c) {
            const float4 p = *(const float4*)(ph + (size_t)c * DH * DH + i * DH + j4 * 4);
            sum.x += p.x; sum.y += p.y; sum.z += p.z; sum.w += p.w;
        }
        const float r = rz[i];
        ct[(j4 * 4 + 0) * DH + i] = (_Float16)(sum.x * r);
        ct[(j4 * 4 + 1) * DH + i] = (_Float16)(sum.y * r);
        ct[(j4 * 4 + 2) * DH + i] = (_Float16)(sum.z * r);
        ct[(j4 * 4 + 3) * DH + i] = (_Float16)(sum.w * r);
    }
}

// ---------------------------------------------------------------------------
// Kernel 3: out[j][s] = rw[s] * sum_i czT[j][i] * eq[i][s]
// grid (32 s-blocks x 32 heads), 256 thr, 4 rounds of 64 s, 2 barriers/round.
// A-frags loaded once from global czT (8 KiB/head, L2-hot from kernel 2).
// ---------------------------------------------------------------------------
__global__ __launch_bounds__(256)
void out_kernel(const float* __restrict__ Q, const _Float16* __restrict__ czT,
                float* __restrict__ out)
{
    const int head = blockIdx.y;
    const int sb   = blockIdx.x;
    const int t    = threadIdx.x;
    const int lane = t & 63;
    const int w    = t >> 6;
    const int ln   = lane & 15;
    const int q8   = lane >> 4;

    __shared__ __align__(16) float    qf[64 * 68];   // fp32 natural [i][s]
    __shared__ __align__(16) _Float16 eqT[64 * 64];  // [s][i] fp16, XOR-chunk swizzle
    __shared__ __align__(16) float    wred[64 * 4];  // [s][4 partials]

    const float* qh = Q + (size_t)head * DH * SEQ;
    const int r0 = t >> 4;
    const int sc = 4 * (t & 15);
    const int s0 = sb * 256;

    float4 pq[4];
    #pragma unroll
    for (int p = 0; p < 4; ++p)
        pq[p] = *(const float4*)(qh + (size_t)(r0 + 16 * p) * SEQ + s0 + sc);

    // persistent A-frags from global czT
    const _Float16* ch = czT + (size_t)head * DH * DH;
    const half8 a0 = *(const half8*)(ch + (16 * w + ln) * DH + 0  + q8 * 8);
    const half8 a1 = *(const half8*)(ch + (16 * w + ln) * DH + 32 + q8 * 8);

    for (int r = 0; r < 4; ++r) {
        #pragma unroll
        for (int p = 0; p < 4; ++p)
            *(float4*)(qf + (r0 + 16 * p) * 68 + sc) = pq[p];
        __syncthreads();
        // transpose + exp + column-sum partials
        {
            const int s  = t & 63;
            const int cg = t >> 6;
            float wsum = 0.f;
            #pragma unroll
            for (int h2 = 0; h2 < 2; ++h2) {
                const int cc = cg + 4 * h2;
                half8 p8;
                #pragma unroll
                for (int jj = 0; jj < 8; ++jj) {
                    const float e = __expf(qf[(8 * cc + jj) * 68 + s]);
                    wsum += e;
                    p8[jj] = (_Float16)e;
                }
                *(half8*)(eqT + s * 64 + ((cc ^ (s & 7)) * 8)) = p8;
            }
            wred[s * 4 + cg] = wsum;
        }
        if (r < 3) {
            #pragma unroll
            for (int p = 0; p < 4; ++p)
                pq[p] = *(const float4*)(qh + (size_t)(r0 + 16 * p) * SEQ
                                         + s0 + (r + 1) * 64 + sc);
        }
        __syncthreads();
        // per-thread softmax denom for this thread's 4 output columns
        float rw[4];
        #pragma unroll
        for (int nt = 0; nt < 4; ++nt) {
            const int s2 = 16 * nt + ln;
            const float4 wv = *(const float4*)(wred + s2 * 4);
            rw[nt] = QSCALE / (wv.x + wv.y + wv.z + wv.w);
        }
        floatx4 acc[4];
        #pragma unroll
        for (int nt = 0; nt < 4; ++nt) acc[nt] = (floatx4){0.f, 0.f, 0.f, 0.f};
        #pragma unroll
        for (int st = 0; st < 2; ++st) {
            const half8 a = (st == 0) ? a0 : a1;
            #pragma unroll
            for (int nt = 0; nt < 4; ++nt) {
                const int s2 = 16 * nt + ln;
                const int cc = st * 4 + q8;
                const half8 b = *(const half8*)(eqT + s2 * 64 + ((cc ^ (s2 & 7)) * 8));
                acc[nt] = __builtin_amdgcn_mfma_f32_16x16x32_f16(a, b, acc[nt], 0, 0, 0);
            }
        }
        float* oh = out + (size_t)head * DH * SEQ + s0 + r * 64;
        #pragma unroll
        for (int nt = 0; nt < 4; ++nt) {
            const int s2 = 16 * nt + ln;
            #pragma unroll
            for (int rr = 0; rr < 4; ++rr) {
                const int j = 16 * w + q8 * 4 + rr;
                oh[(size_t)j * SEQ + s2] = acc[nt][rr] * rw[nt];
            }
        }
    }
}

extern "C" void kernel_launch(void* const* d_in, const int* in_sizes, int n_in,
                              void* d_out, int out_size, void* d_ws, size_t ws_size,
                              hipStream_t stream)
{
    const float* q = (const float*)d_in[0];
    const float* k = (const float*)d_in[1];
    const float* v = (const float*)d_in[2];
    float* out = (float*)d_out;

    float*    partial = (float*)d_ws;                          // 8 MiB
    float*    Zp      = partial + BHEADS * NCHUNK * DH * DH;   // 128 KiB
    _Float16* czT     = (_Float16*)(Zp + BHEADS * NCHUNK * DH); // 256 KiB

    ctx_partial_kernel<<<dim3(NCHUNK, BHEADS), 256, 0, stream>>>(k, v, partial, Zp);
    reduce_kernel<<<BHEADS, 256, 0, stream>>>(partial, Zp, czT);
    out_kernel<<<dim3(32, BHEADS), 256, 0, stream>>>(q, czT, out);
}

// Round 4
// 235.404 us; speedup vs baseline: 1.0139x; 1.0139x over previous
//
#include <hip/hip_runtime.h>
#include <math.h>

// LinearAttend: B=4, N=8, D=64, S=8192, fp32 in/out.
// out[j,s] = (QSCALE/W_s) * sum_i (ctx[i,j]/Z_i) * exp(q[i,s])
//   ctx[i,j] = sum_s exp(k[i,s]) * v[j,s],  Z_i = sum_s exp(k[i,s])
// 3-kernel pipeline, zero atomics:
//   1) ctx_partial: 32-way split-K fp16-MFMA partials (1024 blocks = 4/CU)
//   2) reduce: sum 32 chunk-partials, fold 1/Z, emit fp16 czT[j][i]
//   3) out: 32x32x16 fp16 MFMA -> full-cacheline stores (no L2 RMW)

typedef _Float16 half8 __attribute__((ext_vector_type(8)));
typedef float floatx4 __attribute__((ext_vector_type(4)));
typedef float floatx16 __attribute__((ext_vector_type(16)));

constexpr int BHEADS = 32;
constexpr int DH     = 64;
constexpr int SEQ    = 8192;
constexpr int NCHUNK = 32;          // split-K chunks of 256 s
constexpr float QSCALE = 0.125f;    // 64^-0.5

// ---------------------------------------------------------------------------
// Kernel 1: partial[head][chunk][i][j] = sum_{s in chunk} e[i,s]*v[j,s]
//           Zp[head][chunk][i]         = sum_{s in chunk} e[i,s]
// grid (32 chunks x 32 heads) = 1024 blocks (4/CU), 4 rounds of 64 s.
// ---------------------------------------------------------------------------
__global__ __launch_bounds__(256)
void ctx_partial_kernel(const float* __restrict__ K, const float* __restrict__ V,
                        float* __restrict__ partial, float* __restrict__ Zp)
{
    const int head  = blockIdx.y;
    const int chunk = blockIdx.x;
    const int t     = threadIdx.x;
    const int lane  = t & 63;
    const int w     = t >> 6;
    const int ln    = lane & 15;
    const int q8    = lane >> 4;

    const float* kh = K + (size_t)head * DH * SEQ;
    const float* vh = V + (size_t)head * DH * SEQ;

    __shared__ __align__(16) _Float16 et[64 * 72];  // stride 72 halves = 144 B
    __shared__ __align__(16) _Float16 vt[64 * 72];
    __shared__ __align__(16) float zred[64 * 8];

    // staging map: rows {r0, r0+32}, cols c0..c0+7 (half8 b128 writes)
    const int r0 = t >> 3;           // 0..31
    const int c0 = 8 * (t & 7);      // 0..56
    const int s_blk = chunk * 256;

    float4 pk[2][2], pv[2][2];
    #pragma unroll
    for (int rr = 0; rr < 2; ++rr) {
        const size_t base = (size_t)(r0 + 32 * rr) * SEQ + s_blk + c0;
        pk[rr][0] = *(const float4*)(kh + base);
        pk[rr][1] = *(const float4*)(kh + base + 4);
        pv[rr][0] = *(const float4*)(vh + base);
        pv[rr][1] = *(const float4*)(vh + base + 4);
    }

    floatx4 acc[4];
    #pragma unroll
    for (int jt = 0; jt < 4; ++jt) acc[jt] = (floatx4){0.f, 0.f, 0.f, 0.f};
    float zacc[2] = {0.f, 0.f};

    for (int ts = 0; ts < 4; ++ts) {
        #pragma unroll
        for (int rr = 0; rr < 2; ++rr) {
            const int row = r0 + 32 * rr;
            float e[8];
            e[0] = __expf(pk[rr][0].x); e[1] = __expf(pk[rr][0].y);
            e[2] = __expf(pk[rr][0].z); e[3] = __expf(pk[rr][0].w);
            e[4] = __expf(pk[rr][1].x); e[5] = __expf(pk[rr][1].y);
            e[6] = __expf(pk[rr][1].z); e[7] = __expf(pk[rr][1].w);
            zacc[rr] += e[0]+e[1]+e[2]+e[3]+e[4]+e[5]+e[6]+e[7];
            half8 he, hv;
            #pragma unroll
            for (int x = 0; x < 4; ++x) {
                he[x] = (_Float16)e[x]; he[x+4] = (_Float16)e[x+4];
            }
            hv[0] = (_Float16)pv[rr][0].x; hv[1] = (_Float16)pv[rr][0].y;
            hv[2] = (_Float16)pv[rr][0].z; hv[3] = (_Float16)pv[rr][0].w;
            hv[4] = (_Float16)pv[rr][1].x; hv[5] = (_Float16)pv[rr][1].y;
            hv[6] = (_Float16)pv[rr][1].z; hv[7] = (_Float16)pv[rr][1].w;
            *(half8*)(et + row * 72 + c0) = he;
            *(half8*)(vt + row * 72 + c0) = hv;
        }
        // issue next round's loads immediately after pq consumption
        if (ts < 3) {
            #pragma unroll
            for (int rr = 0; rr < 2; ++rr) {
                const size_t base = (size_t)(r0 + 32 * rr) * SEQ + s_blk
                                    + (ts + 1) * 64 + c0;
                pk[rr][0] = *(const float4*)(kh + base);
                pk[rr][1] = *(const float4*)(kh + base + 4);
                pv[rr][0] = *(const float4*)(vh + base);
                pv[rr][1] = *(const float4*)(vh + base + 4);
            }
        }
        __syncthreads();
        #pragma unroll
        for (int st = 0; st < 2; ++st) {
            const half8 a = *(const half8*)(et + (16 * w + ln) * 72 + st * 32 + q8 * 8);
            #pragma unroll
            for (int jt = 0; jt < 4; ++jt) {
                const half8 b = *(const half8*)(vt + (16 * jt + ln) * 72 + st * 32 + q8 * 8);
                acc[jt] = __builtin_amdgcn_mfma_f32_16x16x32_f16(a, b, acc[jt], 0, 0, 0);
            }
        }
        __syncthreads();
    }

    float* ph = partial + (size_t)(head * NCHUNK + chunk) * DH * DH;
    #pragma unroll
    for (int jt = 0; jt < 4; ++jt) {
        #pragma unroll
        for (int rr = 0; rr < 4; ++rr) {
            const int i = 16 * w + q8 * 4 + rr;
            const int j = 16 * jt + ln;
            ph[i * DH + j] = acc[jt][rr];
        }
    }
    zred[r0 * 8 + (t & 7)] = zacc[0];
    zred[(r0 + 32) * 8 + (t & 7)] = zacc[1];
    __syncthreads();
    if (t < 64) {
        const float4 z0 = *(const float4*)(zred + t * 8);
        const float4 z1 = *(const float4*)(zred + t * 8 + 4);
        Zp[(head * NCHUNK + chunk) * DH + t] =
            z0.x + z0.y + z0.z + z0.w + z1.x + z1.y + z1.z + z1.w;
    }
}

// ---------------------------------------------------------------------------
// Kernel 2: czT[head][j][i] = (1/Z_i) * sum_c partial[head][c][i][j]  (fp16)
// grid 128 blocks: (head, i-quad). Partials are L2-resident.
// ---------------------------------------------------------------------------
__global__ __launch_bounds__(256)
void reduce_kernel(const float* __restrict__ partial, const float* __restrict__ Zp,
                   _Float16* __restrict__ czT)
{
    const int h  = blockIdx.x >> 2;
    const int iq = blockIdx.x & 3;        // i rows [16*iq, 16*iq+16)
    const int t  = threadIdx.x;
    __shared__ float rz[16];

    if (t < 16) {
        float z = 0.f;
        #pragma unroll
        for (int c = 0; c < NCHUNK; ++c)
            z += Zp[(h * NCHUNK + c) * DH + 16 * iq + t];
        rz[t] = 1.0f / z;
    }
    __syncthreads();

    const int il = t >> 4;                // 0..15
    const int j4 = t & 15;
    const int i  = 16 * iq + il;
    const float* ph = partial + (size_t)h * NCHUNK * DH * DH;
    float4 sum = {0.f, 0.f, 0.f, 0.f};
    #pragma unroll
    for (int c = 0; c < NCHUNK; ++c) {
        const float4 p = *(const float4*)(ph + (size_t)c * DH * DH + i * DH + j4 * 4);
        sum.x += p.x; sum.y += p.y; sum.z += p.z; sum.w += p.w;
    }
    const float r = rz[il];
    _Float16* ct = czT + (size_t)h * DH * DH;
    ct[(j4 * 4 + 0) * DH + i] = (_Float16)(sum.x * r);
    ct[(j4 * 4 + 1) * DH + i] = (_Float16)(sum.y * r);
    ct[(j4 * 4 + 2) * DH + i] = (_Float16)(sum.z * r);
    ct[(j4 * 4 + 3) * DH + i] = (_Float16)(sum.w * r);
}

// ---------------------------------------------------------------------------
// Kernel 3: out[j][s] = rw[s] * sum_i czT[j][i] * eq[i][s]
// grid (64 s-blocks x 32 heads) = 2048 blocks, 2 rounds of 64 s.
// 32x32x16 MFMA: C col spans 32 s -> every store = two full 128-B lines.
//   A[m=lane&31][k=8*(lane>>5)+j], B[n=lane&31][k=8*(lane>>5)+j]
//   C/D: col=lane&31, row=(reg&3)+8*(reg>>2)+4*(lane>>5)   [m74/m101]
// ---------------------------------------------------------------------------
__global__ __launch_bounds__(256)
void out_kernel(const float* __restrict__ Q, const _Float16* __restrict__ czT,
                float* __restrict__ out)
{
    const int head = blockIdx.y;
    const int sb   = blockIdx.x;
    const int t    = threadIdx.x;
    const int lane = t & 63;
    const int w    = t >> 6;
    const int l31  = lane & 31;
    const int lh   = lane >> 5;
    const int jw   = 32 * (w & 1);        // wave's j-strip
    const int sw   = 32 * (w >> 1);       // wave's s-strip within round

    __shared__ __align__(16) float    qf[64 * 68];   // fp32 natural [i][s]
    __shared__ __align__(16) _Float16 eqT[64 * 64];  // [s][i] fp16, XOR-chunk swizzle
    __shared__ __align__(16) float    wred[64 * 4];  // [s][4 partials]

    const float* qh = Q + (size_t)head * DH * SEQ;
    const int r0 = t >> 4;
    const int sc = 4 * (t & 15);
    const int s0 = sb * 128;

    float4 pq[4];
    #pragma unroll
    for (int p = 0; p < 4; ++p)
        pq[p] = *(const float4*)(qh + (size_t)(r0 + 16 * p) * SEQ + s0 + sc);

    // persistent A-frags from global czT (L2-hot, 8 KiB/head)
    const _Float16* ch = czT + (size_t)head * DH * DH;
    half8 afr[4];
    #pragma unroll
    for (int st = 0; st < 4; ++st)
        afr[st] = *(const half8*)(ch + (jw + l31) * DH + st * 16 + lh * 8);

    for (int r = 0; r < 2; ++r) {
        #pragma unroll
        for (int p = 0; p < 4; ++p)
            *(float4*)(qf + (r0 + 16 * p) * 68 + sc) = pq[p];
        // issue next round's loads right after consumption
        if (r < 1) {
            #pragma unroll
            for (int p = 0; p < 4; ++p)
                pq[p] = *(const float4*)(qh + (size_t)(r0 + 16 * p) * SEQ
                                         + s0 + 64 + sc);
        }
        __syncthreads();
        // transpose + exp + column-sum partials
        {
            const int s  = t & 63;
            const int cg = t >> 6;
            float wsum = 0.f;
            #pragma unroll
            for (int h2 = 0; h2 < 2; ++h2) {
                const int cc = cg + 4 * h2;
                half8 p8;
                #pragma unroll
                for (int jj = 0; jj < 8; ++jj) {
                    const float e = __expf(qf[(8 * cc + jj) * 68 + s]);
                    wsum += e;
                    p8[jj] = (_Float16)e;
                }
                *(half8*)(eqT + s * 64 + ((cc ^ (s & 7)) * 8)) = p8;
            }
            wred[s * 4 + cg] = wsum;
        }
        __syncthreads();
        // per-lane softmax denom for this lane's s column
        const float4 wv = *(const float4*)(wred + (sw + l31) * 4);
        const float rw = QSCALE / (wv.x + wv.y + wv.z + wv.w);
        // 32x32 tile: 4 K-steps of 16
        floatx16 acc = {};
        #pragma unroll
        for (int st = 0; st < 4; ++st) {
            const int s2 = sw + l31;
            const int cc = 2 * st + lh;
            const half8 b = *(const half8*)(eqT + s2 * 64 + ((cc ^ (s2 & 7)) * 8));
            acc = __builtin_amdgcn_mfma_f32_32x32x16_f16(afr[st], b, acc, 0, 0, 0);
        }
        // full-line stores: lanes 0..31 cover 128 B at row j1, lanes 32..63 row j1+4
        float* oh = out + (size_t)head * DH * SEQ + s0 + r * 64;
        #pragma unroll
        for (int rg = 0; rg < 16; ++rg) {
            const int j = jw + (rg & 3) + 8 * (rg >> 2) + 4 * lh;
            oh[(size_t)j * SEQ + sw + l31] = acc[rg] * rw;
        }
    }
}

extern "C" void kernel_launch(void* const* d_in, const int* in_sizes, int n_in,
                              void* d_out, int out_size, void* d_ws, size_t ws_size,
                              hipStream_t stream)
{
    const float* q = (const float*)d_in[0];
    const float* k = (const float*)d_in[1];
    const float* v = (const float*)d_in[2];
    float* out = (float*)d_out;

    float*    partial = (float*)d_ws;                           // 16 MiB
    float*    Zp      = partial + BHEADS * NCHUNK * DH * DH;    // 256 KiB
    _Float16* czT     = (_Float16*)(Zp + BHEADS * NCHUNK * DH); // 256 KiB

    ctx_partial_kernel<<<dim3(NCHUNK, BHEADS), 256, 0, stream>>>(k, v, partial, Zp);
    reduce_kernel<<<BHEADS * 4, 256, 0, stream>>>(partial, Zp, czT);
    out_kernel<<<dim3(64, BHEADS), 256, 0, stream>>>(q, czT, out);
}